// Round 18
// baseline (89.130 us; speedup 1.0000x reference)
//
#include <hip/hip_runtime.h>
#include <math.h>

// PAM module on MFMA, v17: B=4, C=256, H=W=64 -> N=4096, CK=32.
// v17 changes vs v16:
//   - attn: setprio REVERTED (r17: +2.4us, split the softmax∥PV scheduling
//     region; T5 is incompatible with intra-region source pipelining).
//     attn is now byte-identical to v13 (best measured 48.6-49.0 us).
//   - qkv: 512 threads / 8 waves per 64-n block (2 waves/SIMD): wave w
//     handles chunk-group (w&3) x nc-pair ((w>>2)*2+{0,1}). Same x traffic,
//     W-reads x2 (L2-hot), acc 80->40 AGPR. Pure TLP doubling for a
//     latency-bound kernel (1 wave/SIMD was the r4/r15 signature).

#define BB 4
#define CC 256
#define NN 4096
#define CKK 32
#define LOG2E 1.44269504f

typedef __attribute__((ext_vector_type(4))) float f32x4;
typedef __attribute__((ext_vector_type(16))) float f32x16;
typedef __attribute__((ext_vector_type(8))) short short8;
typedef __attribute__((ext_vector_type(4))) short short4v;

static __device__ __forceinline__ ushort f2bf(float f) {
    union { float f; unsigned u; } v; v.f = f;
    unsigned r = v.u + 0x7FFFu + ((v.u >> 16) & 1u);
    return (ushort)(r >> 16);
}
static __device__ __forceinline__ float bf2f(ushort h) {
    union { unsigned u; float f; } v; v.u = ((unsigned)h) << 16;
    return v.f;
}
static __device__ __forceinline__ unsigned pack2(float lo, float hi) {
    unsigned r;
    asm("v_cvt_pk_bf16_f32 %0, %1, %2" : "=v"(r) : "v"(lo), "v"(hi));
    return r;
}
static __device__ __forceinline__ float exp2fast(float x) {
    return __builtin_amdgcn_exp2f(x);   // v_exp_f32
}
// cross-half (lane ^ 32) max/sum via v_permlane32_swap_b32 (pure VALU)
static __device__ __forceinline__ float maxcross(float x) {
    float a = x, b = x;
    asm("v_permlane32_swap_b32 %0, %1" : "+v"(a), "+v"(b));
    return fmaxf(a, b);
}
static __device__ __forceinline__ float addcross(float x) {
    float a = x, b = x;
    asm("v_permlane32_swap_b32 %0, %1" : "+v"(a), "+v"(b));
    return a + b;
}
// async global->LDS, 16B per lane; lds base must be wave-uniform
static __device__ __forceinline__ void gload_lds16(const void* g, void* l) {
    __builtin_amdgcn_global_load_lds(
        (const __attribute__((address_space(1))) void*)g,
        (__attribute__((address_space(3))) void*)l, 16, 0, 0);
}

union PU { unsigned u[8]; short8 v[2]; };

// log2-domain online softmax with defer-max (THR=8). Pure VALU.
static __device__ __forceinline__ void softmax_step(
    const f32x16 s, float& m_i, float& l_p, PU& P, float& al, bool& resc)
{
    float t0 = fmaxf(fmaxf(s[0],  s[1]),  s[2]);
    float t1 = fmaxf(fmaxf(s[3],  s[4]),  s[5]);
    float t2 = fmaxf(fmaxf(s[6],  s[7]),  s[8]);
    float t3 = fmaxf(fmaxf(s[9],  s[10]), s[11]);
    float t4 = fmaxf(fmaxf(s[12], s[13]), s[14]);
    float mx = fmaxf(fmaxf(fmaxf(t0, t1), t2), fmaxf(fmaxf(t3, t4), s[15]));
    mx = maxcross(mx);
    resc = mx > m_i + 8.f;
    const float mn = resc ? mx : m_i;
    al = resc ? exp2fast(m_i - mx) : 1.f;
    float sum0 = 0.f, sum1 = 0.f;
    #pragma unroll
    for (int g2 = 0; g2 < 8; ++g2) {
        const float plo = exp2fast(s[2 * g2]     - mn);
        const float phi = exp2fast(s[2 * g2 + 1] - mn);
        if (g2 & 1) sum1 += plo + phi; else sum0 += plo + phi;
        P.u[g2] = pack2(plo, phi);
    }
    l_p = l_p * al + (sum0 + sum1);
    m_i = mn;
}

// PV over one 32-m unit-major subtile (no rescale inside: branch-free)
static __device__ __forceinline__ void pv_step(
    const ushort* vsub, const PU& P, f32x16 (&acc)[8], int h2, int l31)
{
    #pragma unroll
    for (int cb = 0; cb < 8; ++cb) {
        const short8 A0 = *(const short8*)&vsub[(size_t)h2 * 2048       + (cb * 32 + l31) * 8];
        const short8 A1 = *(const short8*)&vsub[(size_t)(2 + h2) * 2048 + (cb * 32 + l31) * 8];
        acc[cb] = __builtin_amdgcn_mfma_f32_32x32x16_bf16(A0, P.v[0], acc[cb], 0, 0, 0);
        acc[cb] = __builtin_amdgcn_mfma_f32_32x32x16_bf16(A1, P.v[1], acc[cb], 0, 0, 0);
    }
}

// ---------------- k0: pack weights + biases to bf16 ----------------
__global__ __launch_bounds__(256) void pack_w_kernel(
    const float* __restrict__ Wq, const float* __restrict__ bq,
    const float* __restrict__ Wk, const float* __restrict__ bk,
    const float* __restrict__ Wv, const float* __restrict__ bv,
    ushort* __restrict__ Wb, float* __restrict__ bias)
{
    const int o = blockIdx.x;      // 0..319
    const int c = threadIdx.x;     // 0..255
    const float* src; float bsc;
    if (o < 32)      { src = Wq + o * CC;        bsc = bq[o]; }
    else if (o < 64) { src = Wk + (o - 32) * CC; bsc = bk[o - 32]; }
    else             { src = Wv + (o - 64) * CC; bsc = bv[o - 64]; }
    Wb[o * CC + c] = f2bf(src[c]);
    if (c == 0) bias[o] = bsc;
}

// ---------------- k1: QKV projections via MFMA (64 n, 8 waves, 2/SIMD) -----
__global__ __launch_bounds__(512) void qkv_mfma_kernel(
    const ushort* __restrict__ Wb, const float* __restrict__ bias,
    const float* __restrict__ x,
    ushort* __restrict__ Q, ushort* __restrict__ Kt, ushort* __restrict__ Vg)
{
    const int b = blockIdx.y, n0 = blockIdx.x * 64;
    const int tid = threadIdx.x;
    const int w = tid >> 6, lane = tid & 63, l15 = lane & 15, q = lane >> 4;
    const int wq  = w & 3;            // chunk group: 5 chunks of 16 channels
    const int nco = (w >> 2) << 1;    // nc-pair base: 0 or 2

    f32x4 acc[5][2];
    #pragma unroll
    for (int c5 = 0; c5 < 5; ++c5)
        #pragma unroll
        for (int j = 0; j < 2; ++j) acc[c5][j] = (f32x4)0.f;

    const float* xb = x + (size_t)b * CC * NN + n0;

    #pragma unroll
    for (int ks = 0; ks < 8; ++ks) {
        short8 af[5];
        #pragma unroll
        for (int c5 = 0; c5 < 5; ++c5)
            af[c5] = *(const short8*)&Wb[(wq * 80 + c5 * 16 + l15) * CC + ks * 32 + q * 8];
        union { unsigned u[4]; short8 v; } bfu[2];
        #pragma unroll
        for (int j = 0; j < 2; ++j) {
            const int nc = nco + j;
            const float* xp = xb + (size_t)(ks * 32 + q * 8) * NN + nc * 16 + l15;
            bfu[j].u[0] = pack2(xp[0],              xp[(size_t)NN]);
            bfu[j].u[1] = pack2(xp[2 * (size_t)NN], xp[3 * (size_t)NN]);
            bfu[j].u[2] = pack2(xp[4 * (size_t)NN], xp[5 * (size_t)NN]);
            bfu[j].u[3] = pack2(xp[6 * (size_t)NN], xp[7 * (size_t)NN]);
        }
        #pragma unroll
        for (int c5 = 0; c5 < 5; ++c5)
            #pragma unroll
            for (int j = 0; j < 2; ++j)
                acc[c5][j] = __builtin_amdgcn_mfma_f32_16x16x32_bf16(af[c5], bfu[j].v, acc[c5][j], 0, 0, 0);
    }

    // store-side decomposition for the unit-major V layout: m = (nc&1)*16 + l15
    const int kh2b = (l15 >> 2) & 1;                  // h2-select bit of m
    const int jj   = (l15 & 3) + ((l15 >> 3) << 2);   // j slot within unit

    #pragma unroll
    for (int c5 = 0; c5 < 5; ++c5) {
        const int o0 = wq * 80 + c5 * 16;
        float bia[4];
        #pragma unroll
        for (int r = 0; r < 4; ++r) bia[r] = bias[o0 + q * 4 + r];
        if (o0 >= 64) {
            #pragma unroll
            for (int j = 0; j < 2; ++j) {
                const int nc = nco + j;
                const size_t tbase =
                    ((size_t)b * (NN / 32) + (n0 >> 5) + (nc >> 1)) * 8192
                    + (size_t)(((nc & 1) << 1) + kh2b) * 2048 + jj;
                #pragma unroll
                for (int r = 0; r < 4; ++r) {
                    const int c = o0 - 64 + q * 4 + r;
                    Vg[tbase + c * 8] = f2bf(acc[c5][j][r] + bia[r]);
                }
            }
        } else {
            ushort* dst = (o0 < 32) ? Q : Kt;
            const float sc = (o0 < 32) ? LOG2E : 1.0f;   // exp2-domain Q
            const int oo = (o0 & 31) + q * 4;
            #pragma unroll
            for (int j = 0; j < 2; ++j) {
                const int nc = nco + j;
                short4v h;
                #pragma unroll
                for (int r = 0; r < 4; ++r) h[r] = (short)f2bf((acc[c5][j][r] + bia[r]) * sc);
                *(short4v*)&dst[((size_t)b * NN + n0 + nc * 16 + l15) * CKK + oo] = h;
            }
        }
    }
}

// ---------------- k2: flash attention (v13, best measured, no setprio) -----
__global__ __launch_bounds__(256, 2) void attn_mfma_kernel(
    const ushort* __restrict__ Q, const ushort* __restrict__ K,
    const ushort* __restrict__ Vg,
    ushort* __restrict__ Op, float* __restrict__ Mp, float* __restrict__ Lp,
    int G, int NSEG)
{
    __shared__ __align__(16) ushort vs[2][16384];   // 2 x 32KB 64-m unit-major tiles

    const int id = blockIdx.x;
    const int xcd = id & 7, ix = id >> 3;
    const int b = xcd >> 1;
    int g, row;
    if (G == 4) { g = ((xcd & 1) << 1) | (ix & 1); row = ix >> 1; }
    else        { g = xcd & 1;                     row = ix; }
    const int n0 = row * 128;

    const int tid = threadIdx.x;
    const int w = tid >> 6, lane = tid & 63;
    const int l31 = lane & 31, h2 = lane >> 5;
    const int n0w = n0 + w * 32;          // lane owns n = n0w + l31

    const size_t qrow = ((size_t)b * NN + n0w + l31) * CKK;
    const short8 qB0 = *(const short8*)&Q[qrow + h2 * 8];
    const short8 qB1 = *(const short8*)&Q[qrow + 16 + h2 * 8];

    f32x16 acc[8];                         // O^T: D[c = cb*32 + rowmap(r,h2)][n=l31]
    #pragma unroll
    for (int cb = 0; cb < 8; ++cb) acc[cb] = (f32x16)0.f;
    float m_i = -3.0e38f, l_p = 0.f;       // log2 domain

    const int m_start = g * NSEG;
    const int NT = NSEG / 64;              // 64-m tiles
    const ushort* Kb = K + (size_t)b * NN * CKK;
    const char* Vseg = (const char*)Vg
        + ((size_t)b * (NN / 32) + (size_t)(m_start >> 5)) * 16384;

    const int goff = (w << 10) + (lane << 4);   // per-lane byte offset in a 4KB round
    const int loff = (w << 10);                 // wave-uniform LDS byte offset

    PU Pp, Pc; float alp, alc; bool rp, rc;

    // ---- prologue: DMA tile 0; S(0); K(1) prefetch; softmax(0) ----
    #pragma unroll
    for (int i = 0; i < 8; ++i)
        gload_lds16(Vseg + (i << 12) + goff, (char*)&vs[0][0] + (i << 12) + loff);

    short8 kA0 = *(const short8*)&Kb[(size_t)(m_start + l31) * CKK + h2 * 8];
    short8 kA1 = *(const short8*)&Kb[(size_t)(m_start + l31) * CKK + 16 + h2 * 8];
    {
        f32x16 s = __builtin_amdgcn_mfma_f32_32x32x16_bf16(kA0, qB0, (f32x16)0.f, 0, 0, 0);
        s = __builtin_amdgcn_mfma_f32_32x32x16_bf16(kA1, qB1, s, 0, 0, 0);
        const size_t kr = (size_t)(m_start + 32 + l31) * CKK;
        kA0 = *(const short8*)&Kb[kr + h2 * 8];
        kA1 = *(const short8*)&Kb[kr + 16 + h2 * 8];
        softmax_step(s, m_i, l_p, Pp, alp, rp);   // al(0) irrelevant: acc == 0
    }

    // ---- steady-state: per tile, 1 barrier; softmax(u+1) ∥ PV(u) ----
    for (int t = 0; t < NT - 1; ++t) {
        __syncthreads();                   // buf[t&1] DMA drained; buf[(t+1)&1] free
        const char* Vtn = Vseg + (size_t)(t + 1) * 32768;
        #pragma unroll
        for (int i = 0; i < 8; ++i)
            gload_lds16(Vtn + (i << 12) + goff,
                        (char*)&vs[(t + 1) & 1][0] + (i << 12) + loff);
        const ushort* vb = &vs[t & 1][0];

        // half A: softmax(2t+1) ∥ PV(2t); then rescale by alpha(2t+1)
        {
            f32x16 sn = __builtin_amdgcn_mfma_f32_32x32x16_bf16(kA0, qB0, (f32x16)0.f, 0, 0, 0);
            sn = __builtin_amdgcn_mfma_f32_32x32x16_bf16(kA1, qB1, sn, 0, 0, 0);
            const size_t kr = (size_t)(m_start + (2 * t + 2) * 32 + l31) * CKK;
            kA0 = *(const short8*)&Kb[kr + h2 * 8];
            kA1 = *(const short8*)&Kb[kr + 16 + h2 * 8];
            softmax_step(sn, m_i, l_p, Pc, alc, rc);
            pv_step(vb, Pp, acc, h2, l31);            // independent of softmax above
            if (__any(rc)) {
                #pragma unroll
                for (int cb = 0; cb < 8; ++cb) acc[cb] *= alc;
            }
        }
        // half B: softmax(2t+2) ∥ PV(2t+1); then rescale by alpha(2t+2)
        {
            f32x16 sn = __builtin_amdgcn_mfma_f32_32x32x16_bf16(kA0, qB0, (f32x16)0.f, 0, 0, 0);
            sn = __builtin_amdgcn_mfma_f32_32x32x16_bf16(kA1, qB1, sn, 0, 0, 0);
            const size_t kr = (size_t)(m_start + (2 * t + 3) * 32 + l31) * CKK;
            kA0 = *(const short8*)&Kb[kr + h2 * 8];
            kA1 = *(const short8*)&Kb[kr + 16 + h2 * 8];
            softmax_step(sn, m_i, l_p, Pp, alp, rp);
            pv_step(vb + 8192, Pc, acc, h2, l31);
            if (__any(rp)) {
                #pragma unroll
                for (int cb = 0; cb < 8; ++cb) acc[cb] *= alp;
            }
        }
    }

    // ---- tail tile (t = NT-1): softmax(2NT-1) ∥ PV(2NT-2); final PV ----
    __syncthreads();
    {
        const ushort* vb = &vs[(NT - 1) & 1][0];
        f32x16 sn = __builtin_amdgcn_mfma_f32_32x32x16_bf16(kA0, qB0, (f32x16)0.f, 0, 0, 0);
        sn = __builtin_amdgcn_mfma_f32_32x32x16_bf16(kA1, qB1, sn, 0, 0, 0);
        softmax_step(sn, m_i, l_p, Pc, alc, rc);
        pv_step(vb, Pp, acc, h2, l31);
        if (__any(rc)) {
            #pragma unroll
            for (int cb = 0; cb < 8; ++cb) acc[cb] *= alc;
        }
        pv_step(vb + 8192, Pc, acc, h2, l31);
    }

    // ---- epilogue ----
    const float l = addcross(l_p);         // VALU cross-half sum
    const float linv = 1.f / l;
    if (h2 == 0) {
        const size_t idx = (size_t)(g * BB + b) * NN + n0w + l31;
        Mp[idx] = m_i;                               // log2 domain
        Lp[idx] = l;
    }
    ushort* ob = Op + (size_t)(g * BB + b) * CC * NN;
    #pragma unroll
    for (int cb = 0; cb < 8; ++cb)
        #pragma unroll
        for (int r = 0; r < 16; ++r) {
            const int c = cb * 32 + (r & 3) + 8 * (r >> 2) + 4 * h2;
            ob[(size_t)c * NN + n0w + l31] = f2bf(acc[cb][r] * linv);
        }
}

// ---------------- k3: combine, vectorized (log2-domain Mp) ----------------
template<int G>
__global__ __launch_bounds__(256) void combine_kernel(
    const ushort* __restrict__ Op, const float* __restrict__ Mp,
    const float* __restrict__ Lp, const float* __restrict__ x,
    const float* __restrict__ gamma, float* __restrict__ out)
{
    const int gid = blockIdx.x * 256 + threadIdx.x;   // 0 .. B*C*(N/8)-1
    const int grp   = gid & (NN / 8 - 1);             // 0..511
    const int rowid = gid >> 9;                       // b*CC + c
    const int b = rowid >> 8;
    const int c = rowid & (CC - 1);
    const int n0 = grp * 8;

    f32x4 mp[G][2], lp[G][2];
    #pragma unroll
    for (int g = 0; g < G; ++g) {
        const size_t base = (size_t)(g * BB + b) * NN + n0;
        mp[g][0] = *(const f32x4*)&Mp[base];
        mp[g][1] = *(const f32x4*)&Mp[base + 4];
        lp[g][0] = *(const f32x4*)&Lp[base];
        lp[g][1] = *(const f32x4*)&Lp[base + 4];
    }
    float wgt[G][8];
    #pragma unroll
    for (int h = 0; h < 2; ++h) {
        #pragma unroll
        for (int j = 0; j < 4; ++j) {
            float M = -3.0e38f;
            #pragma unroll
            for (int g = 0; g < G; ++g) M = fmaxf(M, mp[g][h][j]);
            float ws = 0.f;
            #pragma unroll
            for (int g = 0; g < G; ++g) {
                const float wv = lp[g][h][j] * exp2fast(mp[g][h][j] - M);
                wgt[g][h * 4 + j] = wv;
                ws += wv;
            }
            const float inv = 1.f / ws;
            #pragma unroll
            for (int g = 0; g < G; ++g) wgt[g][h * 4 + j] *= inv;
        }
    }

    short8 opv[G];
    #pragma unroll
    for (int g = 0; g < G; ++g)
        opv[g] = *(const short8*)&Op[((size_t)(g * BB + b) * CC + c) * NN + n0];

    const size_t xbase = ((size_t)b * CC + c) * NN + n0;
    const f32x4 x0 = *(const f32x4*)&x[xbase];
    const f32x4 x1 = *(const f32x4*)&x[xbase + 4];
    const float gm = gamma[0];

    f32x4 o0, o1;
    #pragma unroll
    for (int j = 0; j < 4; ++j) {
        float a = 0.f, bsum = 0.f;
        #pragma unroll
        for (int g = 0; g < G; ++g) {
            a    += wgt[g][j]     * bf2f((ushort)opv[g][j]);
            bsum += wgt[g][4 + j] * bf2f((ushort)opv[g][4 + j]);
        }
        o0[j] = gm * a + x0[j];
        o1[j] = gm * bsum + x1[j];
    }
    *(f32x4*)&out[xbase]     = o0;
    *(f32x4*)&out[xbase + 4] = o1;
}

extern "C" void kernel_launch(void* const* d_in, const int* in_sizes, int n_in,
                              void* d_out, int out_size, void* d_ws, size_t ws_size,
                              hipStream_t stream) {
    const float* x     = (const float*)d_in[0];
    const float* Wq    = (const float*)d_in[1];
    const float* bq    = (const float*)d_in[2];
    const float* Wk    = (const float*)d_in[3];
    const float* bk    = (const float*)d_in[4];
    const float* Wv    = (const float*)d_in[5];
    const float* bv    = (const float*)d_in[6];
    const float* gamma = (const float*)d_in[7];
    float* out = (float*)d_out;

    char* p = (char*)d_ws;
    ushort* Wb   = (ushort*)(p);                 // 163840
    float*  bias = (float*) (p + 163840);        // 1280   -> 165120
    ushort* Qb   = (ushort*)(p + 165120);        // 1048576 -> 1213696
    ushort* Kb   = (ushort*)(p + 1213696);       // 1048576 -> 2262272
    ushort* Vc   = (ushort*)(p + 2262272);       // 8388608 -> 10650880 (unit-major)
    float*  Mpb  = (float*) (p + 10650880);      // 262144  -> 10913024
    float*  Lpb  = (float*) (p + 10913024);      // 262144  -> 11175168
    ushort* Opb  = (ushort*)(p + 11175168);      // G*8388608
    // G=4 total: 44,729,600 B; G=2 total: 27,952,384 B
    const int G = (ws_size >= (size_t)44729600) ? 4 : 2;

    pack_w_kernel<<<dim3(320), 256, 0, stream>>>(Wq, bq, Wk, bk, Wv, bv, Wb, bias);
    qkv_mfma_kernel<<<dim3(NN / 64, BB), 512, 0, stream>>>(Wb, bias, x, Qb, Kb, Vc);
    attn_mfma_kernel<<<dim3(128 * G), 256, 0, stream>>>(Qb, Kb, Vc, Opb, Mpb, Lpb, G, NN / G);
    const int cblocks = BB * CC * (NN / 8) / 256;   // 2048
    if (G == 4)
        combine_kernel<4><<<dim3(cblocks), 256, 0, stream>>>(Opb, Mpb, Lpb, x, gamma, out);
    else
        combine_kernel<2><<<dim3(cblocks), 256, 0, stream>>>(Opb, Mpb, Lpb, x, gamma, out);
}

// Round 19
// 85.346 us; speedup vs baseline: 1.0443x; 1.0443x over previous
//
#include <hip/hip_runtime.h>
#include <math.h>

// PAM module on MFMA, v18 = v13 exact restoration (session best: 85.38 us).
// B=4, C=256, H=W=64 -> N=4096, CK=32.
// Six rounds of variations (permlane-only, c-half TLP, 32-n qkv, setprio,
// 8-wave qkv) all measured neutral-to-negative vs this configuration:
//   k0: pack W -> bf16 [320][256] + bias[320]
//   k1: QKV MFMA, 64-n blocks, 256 thr, direct fp32 x reads (cvt_pk on the
//       fly), Q pre-scaled by log2(e), V stored unit-major (PV A-frag units)
//   k2: flash attention, 32x32 MFMA, swapped S^T, k-permuted in-register P,
//       gload_lds-DMA'd 64-m V tiles (2x32KB dbuf, 1 barrier/tile),
//       softmax(u+1) ∥ PV(u) software pipeline, log2-domain defer-max,
//       permlane32_swap cross-half reduce, G-way KV split
//   k3: combine partials + gamma*O + x, fully vectorized

#define BB 4
#define CC 256
#define NN 4096
#define CKK 32
#define LOG2E 1.44269504f

typedef __attribute__((ext_vector_type(4))) float f32x4;
typedef __attribute__((ext_vector_type(16))) float f32x16;
typedef __attribute__((ext_vector_type(8))) short short8;
typedef __attribute__((ext_vector_type(4))) short short4v;

static __device__ __forceinline__ ushort f2bf(float f) {
    union { float f; unsigned u; } v; v.f = f;
    unsigned r = v.u + 0x7FFFu + ((v.u >> 16) & 1u);
    return (ushort)(r >> 16);
}
static __device__ __forceinline__ float bf2f(ushort h) {
    union { unsigned u; float f; } v; v.u = ((unsigned)h) << 16;
    return v.f;
}
static __device__ __forceinline__ unsigned pack2(float lo, float hi) {
    unsigned r;
    asm("v_cvt_pk_bf16_f32 %0, %1, %2" : "=v"(r) : "v"(lo), "v"(hi));
    return r;
}
static __device__ __forceinline__ float exp2fast(float x) {
    return __builtin_amdgcn_exp2f(x);   // v_exp_f32
}
// cross-half (lane ^ 32) max/sum via v_permlane32_swap_b32 (pure VALU)
static __device__ __forceinline__ float maxcross(float x) {
    float a = x, b = x;
    asm("v_permlane32_swap_b32 %0, %1" : "+v"(a), "+v"(b));
    return fmaxf(a, b);
}
static __device__ __forceinline__ float addcross(float x) {
    float a = x, b = x;
    asm("v_permlane32_swap_b32 %0, %1" : "+v"(a), "+v"(b));
    return a + b;
}
// async global->LDS, 16B per lane; lds base must be wave-uniform
static __device__ __forceinline__ void gload_lds16(const void* g, void* l) {
    __builtin_amdgcn_global_load_lds(
        (const __attribute__((address_space(1))) void*)g,
        (__attribute__((address_space(3))) void*)l, 16, 0, 0);
}

union PU { unsigned u[8]; short8 v[2]; };

// log2-domain online softmax with defer-max (THR=8). Pure VALU.
static __device__ __forceinline__ void softmax_step(
    const f32x16 s, float& m_i, float& l_p, PU& P, float& al, bool& resc)
{
    float t0 = fmaxf(fmaxf(s[0],  s[1]),  s[2]);
    float t1 = fmaxf(fmaxf(s[3],  s[4]),  s[5]);
    float t2 = fmaxf(fmaxf(s[6],  s[7]),  s[8]);
    float t3 = fmaxf(fmaxf(s[9],  s[10]), s[11]);
    float t4 = fmaxf(fmaxf(s[12], s[13]), s[14]);
    float mx = fmaxf(fmaxf(fmaxf(t0, t1), t2), fmaxf(fmaxf(t3, t4), s[15]));
    mx = maxcross(mx);
    resc = mx > m_i + 8.f;
    const float mn = resc ? mx : m_i;
    al = resc ? exp2fast(m_i - mx) : 1.f;
    float sum0 = 0.f, sum1 = 0.f;
    #pragma unroll
    for (int g2 = 0; g2 < 8; ++g2) {
        const float plo = exp2fast(s[2 * g2]     - mn);
        const float phi = exp2fast(s[2 * g2 + 1] - mn);
        if (g2 & 1) sum1 += plo + phi; else sum0 += plo + phi;
        P.u[g2] = pack2(plo, phi);
    }
    l_p = l_p * al + (sum0 + sum1);
    m_i = mn;
}

// PV over one 32-m unit-major subtile (no rescale inside: branch-free)
static __device__ __forceinline__ void pv_step(
    const ushort* vsub, const PU& P, f32x16 (&acc)[8], int h2, int l31)
{
    #pragma unroll
    for (int cb = 0; cb < 8; ++cb) {
        const short8 A0 = *(const short8*)&vsub[(size_t)h2 * 2048       + (cb * 32 + l31) * 8];
        const short8 A1 = *(const short8*)&vsub[(size_t)(2 + h2) * 2048 + (cb * 32 + l31) * 8];
        acc[cb] = __builtin_amdgcn_mfma_f32_32x32x16_bf16(A0, P.v[0], acc[cb], 0, 0, 0);
        acc[cb] = __builtin_amdgcn_mfma_f32_32x32x16_bf16(A1, P.v[1], acc[cb], 0, 0, 0);
    }
}

// ---------------- k0: pack weights + biases to bf16 ----------------
__global__ __launch_bounds__(256) void pack_w_kernel(
    const float* __restrict__ Wq, const float* __restrict__ bq,
    const float* __restrict__ Wk, const float* __restrict__ bk,
    const float* __restrict__ Wv, const float* __restrict__ bv,
    ushort* __restrict__ Wb, float* __restrict__ bias)
{
    const int o = blockIdx.x;      // 0..319
    const int c = threadIdx.x;     // 0..255
    const float* src; float bsc;
    if (o < 32)      { src = Wq + o * CC;        bsc = bq[o]; }
    else if (o < 64) { src = Wk + (o - 32) * CC; bsc = bk[o - 32]; }
    else             { src = Wv + (o - 64) * CC; bsc = bv[o - 64]; }
    Wb[o * CC + c] = f2bf(src[c]);
    if (c == 0) bias[o] = bsc;
}

// ---------------- k1: QKV projections via MFMA, direct fp32 x reads --------
__global__ __launch_bounds__(256) void qkv_mfma_kernel(
    const ushort* __restrict__ Wb, const float* __restrict__ bias,
    const float* __restrict__ x,
    ushort* __restrict__ Q, ushort* __restrict__ Kt, ushort* __restrict__ Vg)
{
    const int b = blockIdx.y, n0 = blockIdx.x * 64;
    const int tid = threadIdx.x;
    const int w = tid >> 6, lane = tid & 63, l15 = lane & 15, q = lane >> 4;

    f32x4 acc[5][4];
    #pragma unroll
    for (int c5 = 0; c5 < 5; ++c5)
        #pragma unroll
        for (int nc = 0; nc < 4; ++nc) acc[c5][nc] = (f32x4)0.f;

    const float* xb = x + (size_t)b * CC * NN + n0;

    #pragma unroll
    for (int ks = 0; ks < 8; ++ks) {
        short8 af[5];
        #pragma unroll
        for (int c5 = 0; c5 < 5; ++c5)
            af[c5] = *(const short8*)&Wb[(w * 80 + c5 * 16 + l15) * CC + ks * 32 + q * 8];
        union { unsigned u[4]; short8 v; } bfu[4];
        #pragma unroll
        for (int nc = 0; nc < 4; ++nc) {
            const float* xp = xb + (size_t)(ks * 32 + q * 8) * NN + nc * 16 + l15;
            bfu[nc].u[0] = pack2(xp[0],              xp[(size_t)NN]);
            bfu[nc].u[1] = pack2(xp[2 * (size_t)NN], xp[3 * (size_t)NN]);
            bfu[nc].u[2] = pack2(xp[4 * (size_t)NN], xp[5 * (size_t)NN]);
            bfu[nc].u[3] = pack2(xp[6 * (size_t)NN], xp[7 * (size_t)NN]);
        }
        #pragma unroll
        for (int c5 = 0; c5 < 5; ++c5)
            #pragma unroll
            for (int nc = 0; nc < 4; ++nc)
                acc[c5][nc] = __builtin_amdgcn_mfma_f32_16x16x32_bf16(af[c5], bfu[nc].v, acc[c5][nc], 0, 0, 0);
    }

    // store-side decomposition for the unit-major V layout: m = (nc&1)*16 + l15
    const int kh2b = (l15 >> 2) & 1;                  // h2-select bit of m
    const int jj   = (l15 & 3) + ((l15 >> 3) << 2);   // j slot within unit

    #pragma unroll
    for (int c5 = 0; c5 < 5; ++c5) {
        const int o0 = w * 80 + c5 * 16;
        float bia[4];
        #pragma unroll
        for (int r = 0; r < 4; ++r) bia[r] = bias[o0 + q * 4 + r];
        if (o0 >= 64) {
            #pragma unroll
            for (int nc = 0; nc < 4; ++nc) {
                const size_t tbase =
                    ((size_t)b * (NN / 32) + (n0 >> 5) + (nc >> 1)) * 8192
                    + (size_t)(((nc & 1) << 1) + kh2b) * 2048 + jj;
                #pragma unroll
                for (int r = 0; r < 4; ++r) {
                    const int c = o0 - 64 + q * 4 + r;
                    Vg[tbase + c * 8] = f2bf(acc[c5][nc][r] + bia[r]);
                }
            }
        } else {
            ushort* dst = (o0 < 32) ? Q : Kt;
            const float sc = (o0 < 32) ? LOG2E : 1.0f;   // exp2-domain Q
            const int oo = (o0 & 31) + q * 4;
            #pragma unroll
            for (int nc = 0; nc < 4; ++nc) {
                short4v h;
                #pragma unroll
                for (int r = 0; r < 4; ++r) h[r] = (short)f2bf((acc[c5][nc][r] + bia[r]) * sc);
                *(short4v*)&dst[((size_t)b * NN + n0 + nc * 16 + l15) * CKK + oo] = h;
            }
        }
    }
}

// ---------------- k2: flash attention (v13: DS-free softmax, pipelined) ----
__global__ __launch_bounds__(256, 2) void attn_mfma_kernel(
    const ushort* __restrict__ Q, const ushort* __restrict__ K,
    const ushort* __restrict__ Vg,
    ushort* __restrict__ Op, float* __restrict__ Mp, float* __restrict__ Lp,
    int G, int NSEG)
{
    __shared__ __align__(16) ushort vs[2][16384];   // 2 x 32KB 64-m unit-major tiles

    const int id = blockIdx.x;
    const int xcd = id & 7, ix = id >> 3;
    const int b = xcd >> 1;
    int g, row;
    if (G == 4) { g = ((xcd & 1) << 1) | (ix & 1); row = ix >> 1; }
    else        { g = xcd & 1;                     row = ix; }
    const int n0 = row * 128;

    const int tid = threadIdx.x;
    const int w = tid >> 6, lane = tid & 63;
    const int l31 = lane & 31, h2 = lane >> 5;
    const int n0w = n0 + w * 32;          // lane owns n = n0w + l31

    const size_t qrow = ((size_t)b * NN + n0w + l31) * CKK;
    const short8 qB0 = *(const short8*)&Q[qrow + h2 * 8];
    const short8 qB1 = *(const short8*)&Q[qrow + 16 + h2 * 8];

    f32x16 acc[8];                         // O^T: D[c = cb*32 + rowmap(r,h2)][n=l31]
    #pragma unroll
    for (int cb = 0; cb < 8; ++cb) acc[cb] = (f32x16)0.f;
    float m_i = -3.0e38f, l_p = 0.f;       // log2 domain

    const int m_start = g * NSEG;
    const int NT = NSEG / 64;              // 64-m tiles
    const ushort* Kb = K + (size_t)b * NN * CKK;
    const char* Vseg = (const char*)Vg
        + ((size_t)b * (NN / 32) + (size_t)(m_start >> 5)) * 16384;

    const int goff = (w << 10) + (lane << 4);   // per-lane byte offset in a 4KB round
    const int loff = (w << 10);                 // wave-uniform LDS byte offset

    PU Pp, Pc; float alp, alc; bool rp, rc;

    // ---- prologue: DMA tile 0; S(0); K(1) prefetch; softmax(0) ----
    #pragma unroll
    for (int i = 0; i < 8; ++i)
        gload_lds16(Vseg + (i << 12) + goff, (char*)&vs[0][0] + (i << 12) + loff);

    short8 kA0 = *(const short8*)&Kb[(size_t)(m_start + l31) * CKK + h2 * 8];
    short8 kA1 = *(const short8*)&Kb[(size_t)(m_start + l31) * CKK + 16 + h2 * 8];
    {
        f32x16 s = __builtin_amdgcn_mfma_f32_32x32x16_bf16(kA0, qB0, (f32x16)0.f, 0, 0, 0);
        s = __builtin_amdgcn_mfma_f32_32x32x16_bf16(kA1, qB1, s, 0, 0, 0);
        const size_t kr = (size_t)(m_start + 32 + l31) * CKK;
        kA0 = *(const short8*)&Kb[kr + h2 * 8];
        kA1 = *(const short8*)&Kb[kr + 16 + h2 * 8];
        softmax_step(s, m_i, l_p, Pp, alp, rp);   // al(0) irrelevant: acc == 0
    }

    // ---- steady-state: per tile, 1 barrier; softmax(u+1) ∥ PV(u) ----
    for (int t = 0; t < NT - 1; ++t) {
        __syncthreads();                   // buf[t&1] DMA drained; buf[(t+1)&1] free
        const char* Vtn = Vseg + (size_t)(t + 1) * 32768;
        #pragma unroll
        for (int i = 0; i < 8; ++i)
            gload_lds16(Vtn + (i << 12) + goff,
                        (char*)&vs[(t + 1) & 1][0] + (i << 12) + loff);
        const ushort* vb = &vs[t & 1][0];

        // half A: softmax(2t+1) ∥ PV(2t); then rescale by alpha(2t+1)
        {
            f32x16 sn = __builtin_amdgcn_mfma_f32_32x32x16_bf16(kA0, qB0, (f32x16)0.f, 0, 0, 0);
            sn = __builtin_amdgcn_mfma_f32_32x32x16_bf16(kA1, qB1, sn, 0, 0, 0);
            const size_t kr = (size_t)(m_start + (2 * t + 2) * 32 + l31) * CKK;
            kA0 = *(const short8*)&Kb[kr + h2 * 8];
            kA1 = *(const short8*)&Kb[kr + 16 + h2 * 8];
            softmax_step(sn, m_i, l_p, Pc, alc, rc);
            pv_step(vb, Pp, acc, h2, l31);            // independent of softmax above
            if (__any(rc)) {
                #pragma unroll
                for (int cb = 0; cb < 8; ++cb) acc[cb] *= alc;
            }
        }
        // half B: softmax(2t+2) ∥ PV(2t+1); then rescale by alpha(2t+2)
        {
            f32x16 sn = __builtin_amdgcn_mfma_f32_32x32x16_bf16(kA0, qB0, (f32x16)0.f, 0, 0, 0);
            sn = __builtin_amdgcn_mfma_f32_32x32x16_bf16(kA1, qB1, sn, 0, 0, 0);
            const size_t kr = (size_t)(m_start + (2 * t + 3) * 32 + l31) * CKK;
            kA0 = *(const short8*)&Kb[kr + h2 * 8];
            kA1 = *(const short8*)&Kb[kr + 16 + h2 * 8];
            softmax_step(sn, m_i, l_p, Pp, alp, rp);
            pv_step(vb + 8192, Pc, acc, h2, l31);
            if (__any(rp)) {
                #pragma unroll
                for (int cb = 0; cb < 8; ++cb) acc[cb] *= alp;
            }
        }
    }

    // ---- tail tile (t = NT-1): softmax(2NT-1) ∥ PV(2NT-2); final PV ----
    __syncthreads();
    {
        const ushort* vb = &vs[(NT - 1) & 1][0];
        f32x16 sn = __builtin_amdgcn_mfma_f32_32x32x16_bf16(kA0, qB0, (f32x16)0.f, 0, 0, 0);
        sn = __builtin_amdgcn_mfma_f32_32x32x16_bf16(kA1, qB1, sn, 0, 0, 0);
        softmax_step(sn, m_i, l_p, Pc, alc, rc);
        pv_step(vb, Pp, acc, h2, l31);
        if (__any(rc)) {
            #pragma unroll
            for (int cb = 0; cb < 8; ++cb) acc[cb] *= alc;
        }
        pv_step(vb + 8192, Pc, acc, h2, l31);
    }

    // ---- epilogue ----
    const float l = addcross(l_p);         // VALU cross-half sum
    const float linv = 1.f / l;
    if (h2 == 0) {
        const size_t idx = (size_t)(g * BB + b) * NN + n0w + l31;
        Mp[idx] = m_i;                               // log2 domain
        Lp[idx] = l;
    }
    ushort* ob = Op + (size_t)(g * BB + b) * CC * NN;
    #pragma unroll
    for (int cb = 0; cb < 8; ++cb)
        #pragma unroll
        for (int r = 0; r < 16; ++r) {
            const int c = cb * 32 + (r & 3) + 8 * (r >> 2) + 4 * h2;
            ob[(size_t)c * NN + n0w + l31] = f2bf(acc[cb][r] * linv);
        }
}

// ---------------- k3: combine, vectorized (log2-domain Mp) ----------------
template<int G>
__global__ __launch_bounds__(256) void combine_kernel(
    const ushort* __restrict__ Op, const float* __restrict__ Mp,
    const float* __restrict__ Lp, const float* __restrict__ x,
    const float* __restrict__ gamma, float* __restrict__ out)
{
    const int gid = blockIdx.x * 256 + threadIdx.x;   // 0 .. B*C*(N/8)-1
    const int grp   = gid & (NN / 8 - 1);             // 0..511
    const int rowid = gid >> 9;                       // b*CC + c
    const int b = rowid >> 8;
    const int c = rowid & (CC - 1);
    const int n0 = grp * 8;

    f32x4 mp[G][2], lp[G][2];
    #pragma unroll
    for (int g = 0; g < G; ++g) {
        const size_t base = (size_t)(g * BB + b) * NN + n0;
        mp[g][0] = *(const f32x4*)&Mp[base];
        mp[g][1] = *(const f32x4*)&Mp[base + 4];
        lp[g][0] = *(const f32x4*)&Lp[base];
        lp[g][1] = *(const f32x4*)&Lp[base + 4];
    }
    float wgt[G][8];
    #pragma unroll
    for (int h = 0; h < 2; ++h) {
        #pragma unroll
        for (int j = 0; j < 4; ++j) {
            float M = -3.0e38f;
            #pragma unroll
            for (int g = 0; g < G; ++g) M = fmaxf(M, mp[g][h][j]);
            float ws = 0.f;
            #pragma unroll
            for (int g = 0; g < G; ++g) {
                const float wv = lp[g][h][j] * exp2fast(mp[g][h][j] - M);
                wgt[g][h * 4 + j] = wv;
                ws += wv;
            }
            const float inv = 1.f / ws;
            #pragma unroll
            for (int g = 0; g < G; ++g) wgt[g][h * 4 + j] *= inv;
        }
    }

    short8 opv[G];
    #pragma unroll
    for (int g = 0; g < G; ++g)
        opv[g] = *(const short8*)&Op[((size_t)(g * BB + b) * CC + c) * NN + n0];

    const size_t xbase = ((size_t)b * CC + c) * NN + n0;
    const f32x4 x0 = *(const f32x4*)&x[xbase];
    const f32x4 x1 = *(const f32x4*)&x[xbase + 4];
    const float gm = gamma[0];

    f32x4 o0, o1;
    #pragma unroll
    for (int j = 0; j < 4; ++j) {
        float a = 0.f, bsum = 0.f;
        #pragma unroll
        for (int g = 0; g < G; ++g) {
            a    += wgt[g][j]     * bf2f((ushort)opv[g][j]);
            bsum += wgt[g][4 + j] * bf2f((ushort)opv[g][4 + j]);
        }
        o0[j] = gm * a + x0[j];
        o1[j] = gm * bsum + x1[j];
    }
    *(f32x4*)&out[xbase]     = o0;
    *(f32x4*)&out[xbase + 4] = o1;
}

extern "C" void kernel_launch(void* const* d_in, const int* in_sizes, int n_in,
                              void* d_out, int out_size, void* d_ws, size_t ws_size,
                              hipStream_t stream) {
    const float* x     = (const float*)d_in[0];
    const float* Wq    = (const float*)d_in[1];
    const float* bq    = (const float*)d_in[2];
    const float* Wk    = (const float*)d_in[3];
    const float* bk    = (const float*)d_in[4];
    const float* Wv    = (const float*)d_in[5];
    const float* bv    = (const float*)d_in[6];
    const float* gamma = (const float*)d_in[7];
    float* out = (float*)d_out;

    char* p = (char*)d_ws;
    ushort* Wb   = (ushort*)(p);                 // 163840
    float*  bias = (float*) (p + 163840);        // 1280   -> 165120
    ushort* Qb   = (ushort*)(p + 165120);        // 1048576 -> 1213696
    ushort* Kb   = (ushort*)(p + 1213696);       // 1048576 -> 2262272
    ushort* Vc   = (ushort*)(p + 2262272);       // 8388608 -> 10650880 (unit-major)
    float*  Mpb  = (float*) (p + 10650880);      // 262144  -> 10913024
    float*  Lpb  = (float*) (p + 10913024);      // 262144  -> 11175168
    ushort* Opb  = (ushort*)(p + 11175168);      // G*8388608
    // G=4 total: 44,729,600 B; G=2 total: 27,952,384 B
    const int G = (ws_size >= (size_t)44729600) ? 4 : 2;

    pack_w_kernel<<<dim3(320), 256, 0, stream>>>(Wq, bq, Wk, bk, Wv, bv, Wb, bias);
    qkv_mfma_kernel<<<dim3(NN / 64, BB), 256, 0, stream>>>(Wb, bias, x, Qb, Kb, Vc);
    attn_mfma_kernel<<<dim3(128 * G), 256, 0, stream>>>(Qb, Kb, Vc, Opb, Mpb, Lpb, G, NN / G);
    const int cblocks = BB * CC * (NN / 8) / 256;   // 2048
    if (G == 4)
        combine_kernel<4><<<dim3(cblocks), 256, 0, stream>>>(Opb, Mpb, Lpb, x, gamma, out);
    else
        combine_kernel<2><<<dim3(cblocks), 256, 0, stream>>>(Opb, Mpb, Lpb, x, gamma, out);
}